// Round 1
// baseline (835.365 us; speedup 1.0000x reference)
//
#include <hip/hip_runtime.h>
#include <math.h>

// SimpleGCDEC: z = adj @ (x @ W) + b ; q = student-t soft assignment
// N=10000, NFEAT=3000, NHID=32, K=10, ALPHA=0.2
//
// Pipeline (all fp32):
//   1) gemm_nt32: partials of x@W           (grid 40x16)
//   2) reduce_add: support = sum partials   (ws)
//   3) gemm_nt32: partials of adj@support   (grid 40x16)
//   4) reduce_add: z = sum partials + b     (-> d_out[0:320000])
//   5) qkern: q from z                      (-> d_out[320000:420000])

#define NH     32      // NHID
#define KC     32      // K-chunk per staging round
#define TR     256     // tile rows per block
#define LDA_S  36      // KC + 4 pad (word stride) -> A-reads 2-way bank aliased (free)
#define NSPLIT 16      // split-K factor

__global__ __launch_bounds__(256) void gemm_nt32(
    const float* __restrict__ A,   // [M][K]
    const float* __restrict__ B,   // [K][32]
    float* __restrict__ outp,      // [NSPLIT][M][32] partials
    int M, int K, int nchunks)
{
    __shared__ float As[TR * LDA_S];   // 36864 B, [row][k] padded
    __shared__ float Bs[KC * NH];      // 4096 B,  [k][col]

    const int tid  = threadIdx.x;
    const int rg   = tid >> 2;     // 0..63 : row group (rows rg + 64*m)
    const int jg   = tid & 3;      // 0..3  : col group (cols jg*8 .. +7)
    const int row0 = blockIdx.x * TR;
    const int sy   = blockIdx.y;   // split index

    float acc[4][8];
#pragma unroll
    for (int m = 0; m < 4; ++m)
#pragma unroll
        for (int j = 0; j < 8; ++j) acc[m][j] = 0.0f;

    for (int c = sy; c < nchunks; c += NSPLIT) {
        const int k0 = c * KC;

        // ---- stage A tile: 256 rows x 32 k = 2048 float4, 8 per thread
#pragma unroll
        for (int p = 0; p < 8; ++p) {
            int idx = tid + (p << 8);        // 0..2047
            int ar  = idx >> 3;              // 0..255
            int ac4 = idx & 7;               // float4 slot within row
            int gr  = row0 + ar;
            int gk  = k0 + (ac4 << 2);
            float4 v = make_float4(0.f, 0.f, 0.f, 0.f);
            if (gr < M && gk < K)            // K % 4 == 0, so gk<K => gk+3<K
                v = *(const float4*)(A + (size_t)gr * K + gk);
            *(float4*)(&As[ar * LDA_S + (ac4 << 2)]) = v;
        }
        // ---- stage B tile: 32 k x 32 col = 256 float4, 1 per thread
        {
            int brow = tid >> 3;             // 0..31
            int bc4  = tid & 7;
            int gk   = k0 + brow;
            float4 v = make_float4(0.f, 0.f, 0.f, 0.f);
            if (gk < K)
                v = *(const float4*)(B + (size_t)gk * NH + (bc4 << 2));
            *(float4*)(&Bs[brow * NH + (bc4 << 2)]) = v;
        }
        __syncthreads();

        // ---- compute: 4k per iter, 4 rows x 8 cols per thread
#pragma unroll
        for (int kk = 0; kk < KC; kk += 4) {
            float4 a[4];
#pragma unroll
            for (int m = 0; m < 4; ++m)
                a[m] = *(const float4*)(&As[(rg + (m << 6)) * LDA_S + kk]);
#pragma unroll
            for (int t = 0; t < 4; ++t) {
                float4 b0 = *(const float4*)(&Bs[(kk + t) * NH + (jg << 3)]);
                float4 b1 = *(const float4*)(&Bs[(kk + t) * NH + (jg << 3) + 4]);
#pragma unroll
                for (int m = 0; m < 4; ++m) {
                    float av = (t == 0) ? a[m].x : (t == 1) ? a[m].y
                             : (t == 2) ? a[m].z : a[m].w;
                    acc[m][0] += av * b0.x;
                    acc[m][1] += av * b0.y;
                    acc[m][2] += av * b0.z;
                    acc[m][3] += av * b0.w;
                    acc[m][4] += av * b1.x;
                    acc[m][5] += av * b1.y;
                    acc[m][6] += av * b1.z;
                    acc[m][7] += av * b1.w;
                }
            }
        }
        __syncthreads();
    }

    // ---- store partials
    float* op = outp + (size_t)sy * M * NH;
#pragma unroll
    for (int m = 0; m < 4; ++m) {
        int gr = row0 + rg + (m << 6);
        if (gr < M) {
            float4 v0 = make_float4(acc[m][0], acc[m][1], acc[m][2], acc[m][3]);
            float4 v1 = make_float4(acc[m][4], acc[m][5], acc[m][6], acc[m][7]);
            *(float4*)(op + (size_t)gr * NH + (jg << 3))     = v0;
            *(float4*)(op + (size_t)gr * NH + (jg << 3) + 4) = v1;
        }
    }
}

__global__ __launch_bounds__(256) void reduce_add(
    const float* __restrict__ parts,  // [NSPLIT][total4] float4
    const float* __restrict__ bias,   // [32] or nullptr
    float* __restrict__ out,          // [total4] float4
    int total4)
{
    int i = blockIdx.x * blockDim.x + threadIdx.x;
    if (i >= total4) return;
    float4 s = make_float4(0.f, 0.f, 0.f, 0.f);
#pragma unroll
    for (int p = 0; p < NSPLIT; ++p) {
        float4 v = ((const float4*)parts)[(size_t)p * total4 + i];
        s.x += v.x; s.y += v.y; s.z += v.z; s.w += v.w;
    }
    if (bias) {
        float4 bv = ((const float4*)bias)[i & 7];   // f4 slot within the 32-wide row
        s.x += bv.x; s.y += bv.y; s.z += bv.z; s.w += bv.w;
    }
    ((float4*)out)[i] = s;
}

__global__ __launch_bounds__(256) void qkern(
    const float* __restrict__ z,   // [N][32]
    const float* __restrict__ mu,  // [10][32]
    float* __restrict__ q,         // [N][10]
    int N)
{
    const int tid  = threadIdx.x;
    const int lane = tid & 31;
    const int i    = blockIdx.x * 8 + (tid >> 5);
    if (i >= N) return;

    float zv = z[i * 32 + lane];
    float qm = 0.f, qsum = 0.f;
#pragma unroll
    for (int c = 0; c < 10; ++c) {
        float d = zv - mu[c * 32 + lane];
        float p = d * d;
#pragma unroll
        for (int m = 16; m >= 1; m >>= 1) p += __shfl_xor(p, m, 32);
        // q = (1 + d2/alpha + 1e-8)^-(alpha+1) / 2,  alpha = 0.2
        float t  = 1.0f + p * 5.0f + 1e-8f;
        float qc = powf(t, -1.2f) * 0.5f;
        qsum += qc;
        if (lane == c) qm = qc;
    }
    if (lane < 10) q[i * 10 + lane] = qm / qsum;
}

extern "C" void kernel_launch(void* const* d_in, const int* in_sizes, int n_in,
                              void* d_out, int out_size, void* d_ws, size_t ws_size,
                              hipStream_t stream)
{
    const float* x   = (const float*)d_in[0];   // [10000][3000]
    const float* adj = (const float*)d_in[1];   // [10000][10000]
    const float* W   = (const float*)d_in[2];   // [3000][32]
    const float* b   = (const float*)d_in[3];   // [32]
    const float* mu  = (const float*)d_in[4];   // [10][32]

    const int N = 10000, NFEAT = 3000;
    float* z_out = (float*)d_out;               // [10000][32]
    float* q_out = (float*)d_out + N * NH;      // [10000][10]

    float* ws_part    = (float*)d_ws;                           // NSPLIT * 320000 floats
    float* ws_support = (float*)d_ws + (size_t)NSPLIT * N * NH; // 320000 floats

    const int total4   = N * NH / 4;            // 80000
    const int rowBlks  = (N + TR - 1) / TR;     // 40
    const int redBlks  = (total4 + 255) / 256;  // 313

    // 1) support partials = x @ W
    {
        int nchunks = (NFEAT + KC - 1) / KC;    // 94
        gemm_nt32<<<dim3(rowBlks, NSPLIT), 256, 0, stream>>>(
            x, W, ws_part, N, NFEAT, nchunks);
    }
    // 2) support = sum partials
    reduce_add<<<redBlks, 256, 0, stream>>>(ws_part, nullptr, ws_support, total4);
    // 3) z partials = adj @ support
    {
        int nchunks = (N + KC - 1) / KC;        // 313
        gemm_nt32<<<dim3(rowBlks, NSPLIT), 256, 0, stream>>>(
            adj, ws_support, ws_part, N, N, nchunks);
    }
    // 4) z = sum partials + b  -> d_out
    reduce_add<<<redBlks, 256, 0, stream>>>(ws_part, b, z_out, total4);
    // 5) q from z -> d_out + 320000
    qkern<<<(N + 7) / 8, 256, 0, stream>>>(z_out, mu, q_out, N);
}